// Round 4
// baseline (101.669 us; speedup 1.0000x reference)
//
#include <hip/hip_runtime.h>
#include <hip/hip_bf16.h>
#include <math.h>

#define BB 2
#define NN 2048
#define FF 128
#define HH 4
#define HALF 1024

typedef __attribute__((ext_vector_type(8))) short short8;
typedef __attribute__((ext_vector_type(4))) float f32x4;

__device__ __forceinline__ short f2bf(float f){
    __hip_bfloat16 h = __float2bfloat16(f);
    return *reinterpret_cast<short*>(&h);
}
__device__ __forceinline__ float bf2f(short v){
    __hip_bfloat16 h = *reinterpret_cast<__hip_bfloat16*>(&v);
    return __bfloat162float(h);
}

// K0: wv fp32 -> wvB (bf16 row-major copy) + wvT (bf16 transpose)
__global__ void k_transpose(const float* __restrict__ wv, __hip_bfloat16* __restrict__ wvT,
                            __hip_bfloat16* __restrict__ wvB){
    __shared__ float tile[32][33];
    int b = blockIdx.z;
    int i0 = blockIdx.x * 32, j0 = blockIdx.y * 32;
    int tx = threadIdx.x & 31, ty = threadIdx.x >> 5;
    const float* src = wv + (size_t)b * HALF * HALF;
    __hip_bfloat16* dstT = wvT + (size_t)b * HALF * HALF;
    __hip_bfloat16* dstB = wvB + (size_t)b * HALF * HALF;
    #pragma unroll
    for(int l = 0; l < 4; l++){
        int row = ty + l * 8;
        float v = src[(size_t)(j0 + row) * HALF + (i0 + tx)];
        tile[row][tx] = v;
        dstB[(size_t)(j0 + row) * HALF + (i0 + tx)] = __float2bfloat16(v);
    }
    __syncthreads();
    #pragma unroll
    for(int l = 0; l < 4; l++){
        int row = ty + l * 8;
        dstT[(size_t)(i0 + row) * HALF + (j0 + tx)] = __float2bfloat16(tile[tx][row]);
    }
}

// K1: Wh[b][h][n][f] = sum_k x[b][n][k] * W[h][k][f]   (fp32)
__global__ void k_wh(const float* __restrict__ x, const float* __restrict__ W,
                     float* __restrict__ Wh){
    __shared__ float xs[32][FF];
    int n0 = blockIdx.x * 32;
    int h  = blockIdx.y;
    int b  = blockIdx.z;
    int t  = threadIdx.x;
    const float* xb = x + ((size_t)b * NN + n0) * FF;
    #pragma unroll
    for(int l = 0; l < 16; l++){
        int idx = l * 256 + t;
        xs[idx >> 7][idx & 127] = xb[idx];
    }
    __syncthreads();
    int f = t & 127, rh = t >> 7;
    float acc[16];
    #pragma unroll
    for(int r = 0; r < 16; r++) acc[r] = 0.f;
    const float* Wp = W + (size_t)h * FF * FF + f;
    for(int k = 0; k < FF; k++){
        float w = Wp[(size_t)k * FF];
        #pragma unroll
        for(int r = 0; r < 16; r++) acc[r] += xs[rh * 16 + r][k] * w;
    }
    float* o = Wh + (((size_t)b * HH + h) * NN + n0 + rh * 16) * FF + f;
    #pragma unroll
    for(int r = 0; r < 16; r++) o[(size_t)r * FF] = acc[r];
}

// K2: s[row] = Wh[row]·a_src, d[row] = Wh[row]·a_dst
__global__ void k_sd(const float* __restrict__ Wh, const float* __restrict__ a,
                     float* __restrict__ s, float* __restrict__ d){
    int wid = threadIdx.x >> 6, lane = threadIdx.x & 63;
    int row = blockIdx.x * 4 + wid;
    int h = (row / NN) & (HH - 1);
    const float* wr = Wh + (size_t)row * FF;
    float v0 = wr[lane], v1 = wr[lane + 64];
    const float* ah = a + (size_t)h * 2 * FF;
    float ps = v0 * ah[lane]      + v1 * ah[lane + 64];
    float pd = v0 * ah[FF + lane] + v1 * ah[FF + lane + 64];
    #pragma unroll
    for(int m = 32; m >= 1; m >>= 1){
        ps += __shfl_xor(ps, m);
        pd += __shfl_xor(pd, m);
    }
    if(lane == 0){ s[row] = ps; d[row] = pd; }
}

// K3: denom[b][h][jg] = sum_i exp(lrelu(s_i+d_j))*wm ; no P store.
// grid x=jt(8: 128 j), y=ich(32: 32 i), z=bb(4). block 256.
__global__ __launch_bounds__(256) void k_denom(const int* __restrict__ adj,
        const __hip_bfloat16* __restrict__ wvRM, const __hip_bfloat16* __restrict__ wvTp,
        const float* __restrict__ s, const float* __restrict__ d, float* __restrict__ denom){
    int t = threadIdx.x;
    int w = t >> 6, lane = t & 63, q = lane >> 4, r = lane & 15;
    int jt = blockIdx.x, ich = blockIdx.y, bb = blockIdx.z;
    int b = bb >> 1, blk = bb & 1;
    int jl = jt * 128 + w * 32 + q * 8;
    int jg = blk ? jl : HALF + jl;
    int sl = b * HH;
    float dv_[HH][8];
    #pragma unroll
    for(int h = 0; h < HH; h++){
        const float* dp = d + (size_t)(sl + h) * NN + jg;
        float4 d0 = *(const float4*)dp;
        float4 d1 = *(const float4*)(dp + 4);
        dv_[h][0]=d0.x; dv_[h][1]=d0.y; dv_[h][2]=d0.z; dv_[h][3]=d0.w;
        dv_[h][4]=d1.x; dv_[h][5]=d1.y; dv_[h][6]=d1.z; dv_[h][7]=d1.w;
    }
    float accd[HH][8] = {};
    #pragma unroll
    for(int mtl = 0; mtl < 2; mtl++){
        int iloc = ich * 32 + mtl * 16 + r;
        int ig = blk ? HALF + iloc : iloc;
        const int* ap = adj + ((size_t)b * NN + ig) * NN + jg;
        int4 A0 = *(const int4*)ap;
        int4 A1 = *(const int4*)(ap + 4);
        int aa[8] = {A0.x, A0.y, A0.z, A0.w, A1.x, A1.y, A1.z, A1.w};
        const short* wp = (const short*)(blk ? wvRM : wvTp) + ((size_t)b * HALF + iloc) * HALF + jl;
        short8 wb = *(const short8*)wp;
        float wm[8];
        #pragma unroll
        for(int e = 0; e < 8; e++) wm[e] = aa[e] > 0 ? bf2f(wb[e]) : 0.f;
        #pragma unroll
        for(int h = 0; h < HH; h++){
            float sv = s[(size_t)(sl + h) * NN + ig];
            #pragma unroll
            for(int e = 0; e < 8; e++){
                float tt = sv + dv_[h][e];
                tt = tt > 0.f ? tt : 0.2f * tt;
                accd[h][e] += __expf(tt) * wm[e];
            }
        }
    }
    #pragma unroll
    for(int h = 0; h < HH; h++){
        #pragma unroll
        for(int e = 0; e < 8; e++){
            float v = accd[h][e];
            v += __shfl_xor(v, 1);
            v += __shfl_xor(v, 2);
            v += __shfl_xor(v, 4);
            v += __shfl_xor(v, 8);
            accd[h][e] = v;
        }
    }
    if(r == 0){
        #pragma unroll
        for(int h = 0; h < HH; h++)
            #pragma unroll
            for(int e = 0; e < 8; e++)
                atomicAdd(&denom[(size_t)(sl + h) * NN + jg + e], accd[h][e]);
    }
}

// K4: WhB (bf16, MFMA-B-fragment layout) = Wh[j][f] * 1/clip(denom[j])
__global__ __launch_bounds__(256) void k_scale(const float* __restrict__ Wh,
        const float* __restrict__ denom, short* __restrict__ WhB){
    int t = threadIdx.x, w = t >> 6, lane = t & 63, q = lane >> 4, r = lane & 15;
    int kt = blockIdx.x, h = blockIdx.y, b = blockIdx.z;
    int sl = b * HH + h;
    int jb = kt * 32 + q * 8;
    const float* dp = denom + (size_t)sl * NN + jb;
    float4 D0 = *(const float4*)dp;
    float4 D1 = *(const float4*)(dp + 4);
    float dn[8] = {D0.x,D0.y,D0.z,D0.w,D1.x,D1.y,D1.z,D1.w};
    float inv[8];
    #pragma unroll
    for(int e = 0; e < 8; e++) inv[e] = 1.f / fmaxf(dn[e], 1e-12f);
    #pragma unroll
    for(int ntl = 0; ntl < 2; ntl++){
        int nt = w + ntl * 4;
        int f = nt * 16 + r;
        short8 pk;
        #pragma unroll
        for(int e = 0; e < 8; e++){
            float v = Wh[((size_t)sl * NN + jb + e) * FF + f] * inv[e];
            pk[e] = f2bf(v);
        }
        *(short8*)(WhB + (((size_t)sl * 8 + nt) * 64 + kt) * 512 + lane * 8) = pk;
    }
}

// K5: fused PV — rebuild P A-frags in registers (adj+wv+exp), MFMA vs WhB.
// grid: x=mt(64: 16 rows), y=fh(2: 64 f), z=bb(4). block 256 = 4 waves (one per h).
#define LOADK(KT, A0,A1,WV,D0,D1,B0,B1,B2,B3) { \
    int off_ = (KT) * 32 + q8; \
    A0 = *(const int4*)(ap_row + off_); \
    A1 = *(const int4*)(ap_row + off_ + 4); \
    WV = *(const short8*)(wv_row + off_); \
    D0 = *(const float4*)(d_row + off_); \
    D1 = *(const float4*)(d_row + off_ + 4); \
    const short* bp_ = Bk + (size_t)(KT) * 512; \
    B0 = *(const short8*)bp_; \
    B1 = *(const short8*)(bp_ + 32768); \
    B2 = *(const short8*)(bp_ + 65536); \
    B3 = *(const short8*)(bp_ + 98304); }

#define MKA(PK, A0,A1,WV,D0,D1) { \
    int aa_[8] = {A0.x,A0.y,A0.z,A0.w,A1.x,A1.y,A1.z,A1.w}; \
    float dd_[8] = {D0.x,D0.y,D0.z,D0.w,D1.x,D1.y,D1.z,D1.w}; \
    _Pragma("unroll") \
    for(int e = 0; e < 8; e++){ \
        float wmv = aa_[e] > 0 ? bf2f(WV[e]) : 0.f; \
        float tt = sv + dd_[e]; \
        tt = tt > 0.f ? tt : 0.2f * tt; \
        PK[e] = f2bf(__expf(tt) * wmv); } }

__global__ __launch_bounds__(256) void k_pvf(const int* __restrict__ adj,
        const __hip_bfloat16* __restrict__ wvRM, const __hip_bfloat16* __restrict__ wvTp,
        const float* __restrict__ s, const float* __restrict__ d,
        const short* __restrict__ WhB, float* __restrict__ out){
    int t = threadIdx.x;
    int h = t >> 6, lane = t & 63, q = lane >> 4, r = lane & 15;
    int q8 = q * 8;
    int mt = blockIdx.x, fh = blockIdx.y, bb = blockIdx.z;
    int b = bb >> 1, blk = bb & 1;
    int iloc = mt * 16 + r;
    int ig = blk ? HALF + iloc : iloc;
    int sl = b * HH + h;
    int col0 = blk ? 0 : HALF;      // global col of local col 0
    int koff = blk ? 0 : 32;        // global k-tile base for B
    const int* ap_row = adj + ((size_t)b * NN + ig) * NN + col0;
    const short* wv_row = (const short*)(blk ? wvRM : wvTp) + ((size_t)b * HALF + iloc) * HALF;
    const float* d_row = d + (size_t)sl * NN + col0;
    const short* Bk = WhB + ((size_t)(sl * 8 + fh * 4) * 64 + koff) * 512 + lane * 8;
    float sv = s[(size_t)sl * NN + ig];

    int4 a0A, a1A; short8 wA; float4 d0A, d1A; short8 b0A, b1A, b2A, b3A;
    int4 a0B, a1B; short8 wB; float4 d0B, d1B; short8 b0B, b1B, b2B, b3B;
    f32x4 acc0 = {0.f,0.f,0.f,0.f}, acc1 = {0.f,0.f,0.f,0.f};
    f32x4 acc2 = {0.f,0.f,0.f,0.f}, acc3 = {0.f,0.f,0.f,0.f};

    LOADK(0, a0A,a1A,wA,d0A,d1A,b0A,b1A,b2A,b3A)
    for(int kt = 0; kt < 32; kt += 2){
        LOADK(kt + 1, a0B,a1B,wB,d0B,d1B,b0B,b1B,b2B,b3B)
        short8 pk;
        MKA(pk, a0A,a1A,wA,d0A,d1A)
        acc0 = __builtin_amdgcn_mfma_f32_16x16x32_bf16(pk, b0A, acc0, 0, 0, 0);
        acc1 = __builtin_amdgcn_mfma_f32_16x16x32_bf16(pk, b1A, acc1, 0, 0, 0);
        acc2 = __builtin_amdgcn_mfma_f32_16x16x32_bf16(pk, b2A, acc2, 0, 0, 0);
        acc3 = __builtin_amdgcn_mfma_f32_16x16x32_bf16(pk, b3A, acc3, 0, 0, 0);
        if(kt + 2 < 32){
            LOADK(kt + 2, a0A,a1A,wA,d0A,d1A,b0A,b1A,b2A,b3A)
        }
        short8 pk2;
        MKA(pk2, a0B,a1B,wB,d0B,d1B)
        acc0 = __builtin_amdgcn_mfma_f32_16x16x32_bf16(pk2, b0B, acc0, 0, 0, 0);
        acc1 = __builtin_amdgcn_mfma_f32_16x16x32_bf16(pk2, b1B, acc1, 0, 0, 0);
        acc2 = __builtin_amdgcn_mfma_f32_16x16x32_bf16(pk2, b2B, acc2, 0, 0, 0);
        acc3 = __builtin_amdgcn_mfma_f32_16x16x32_bf16(pk2, b3B, acc3, 0, 0, 0);
    }
    // epilogue: C/D layout col = lane&15, row = (lane>>4)*4 + rg
    int rq = lane >> 4, rc = lane & 15;
    int rowg0 = (blk ? HALF : 0) + mt * 16;
    float* ob = out + ((size_t)b * NN + rowg0) * (HH * FF) + h * FF + fh * 64 + rc;
#define STORE(ACC, NI) { \
    float* op = ob + (NI) * 16; \
    _Pragma("unroll") \
    for(int rg = 0; rg < 4; rg++){ \
        float v = ACC[rg]; \
        v = v > 0.f ? v : expm1f(v); \
        op[(size_t)(rq * 4 + rg) * (HH * FF)] = v; } }
    STORE(acc0, 0)
    STORE(acc1, 1)
    STORE(acc2, 2)
    STORE(acc3, 3)
#undef STORE
}

extern "C" void kernel_launch(void* const* d_in, const int* in_sizes, int n_in,
                              void* d_out, int out_size, void* d_ws, size_t ws_size,
                              hipStream_t stream){
    const float* x   = (const float*)d_in[0];
    const float* wv  = (const float*)d_in[1];
    const float* W   = (const float*)d_in[2];
    const float* a   = (const float*)d_in[3];
    const int*   adj = (const int*)d_in[4];
    float* out = (float*)d_out;

    char* ws = (char*)d_ws;
    float*          Wh    = (float*)ws;                          //  8,388,608 B
    short*          WhB   = (short*)(ws + 8388608);              //  4,194,304 B
    __hip_bfloat16* wvT   = (__hip_bfloat16*)(ws + 12582912);    //  4,194,304 B
    __hip_bfloat16* wvB   = (__hip_bfloat16*)(ws + 16777216);    //  4,194,304 B
    float*          s     = (float*)(ws + 20971520);             //     65,536 B
    float*          dv    = (float*)(ws + 21037056);             //     65,536 B
    float*          denom = (float*)(ws + 21102592);             //     65,536 B

    k_transpose<<<dim3(32, 32, BB), 256, 0, stream>>>(wv, wvT, wvB);
    k_wh<<<dim3(64, HH, BB), 256, 0, stream>>>(x, W, Wh);
    k_sd<<<dim3(4096), 256, 0, stream>>>(Wh, a, s, dv);
    hipMemsetAsync(denom, 0, 65536, stream);
    k_denom<<<dim3(8, 32, 4), 256, 0, stream>>>(adj, wvB, wvT, s, dv, denom);
    k_scale<<<dim3(64, HH, BB), 256, 0, stream>>>(Wh, denom, WhB);
    k_pvf<<<dim3(64, 2, 4), 256, 0, stream>>>(adj, wvB, wvT, s, dv, WhB, out);
}

// Round 5
// 86.016 us; speedup vs baseline: 1.1820x; 1.1820x over previous
//
#include <hip/hip_runtime.h>
#include <hip/hip_bf16.h>
#include <math.h>

#define BB 2
#define NN 2048
#define FF 128
#define HH 4
#define HALF 1024

typedef __attribute__((ext_vector_type(8))) short short8;
typedef __attribute__((ext_vector_type(4))) float f32x4;

__device__ __forceinline__ short f2bf(float f){
    __hip_bfloat16 h = __float2bfloat16(f);
    return *reinterpret_cast<short*>(&h);
}
__device__ __forceinline__ float bf2f(short v){
    __hip_bfloat16 h = *reinterpret_cast<__hip_bfloat16*>(&v);
    return __bfloat162float(h);
}

// K0: wv fp32 -> wvB (bf16 row-major) + wvT (bf16 transpose)
__global__ void k_transpose(const float* __restrict__ wv, __hip_bfloat16* __restrict__ wvT,
                            __hip_bfloat16* __restrict__ wvB){
    __shared__ float tile[32][33];
    int b = blockIdx.z;
    int i0 = blockIdx.x * 32, j0 = blockIdx.y * 32;
    int tx = threadIdx.x & 31, ty = threadIdx.x >> 5;
    const float* src = wv + (size_t)b * HALF * HALF;
    __hip_bfloat16* dstT = wvT + (size_t)b * HALF * HALF;
    __hip_bfloat16* dstB = wvB + (size_t)b * HALF * HALF;
    #pragma unroll
    for(int l = 0; l < 4; l++){
        int row = ty + l * 8;
        float v = src[(size_t)(j0 + row) * HALF + (i0 + tx)];
        tile[row][tx] = v;
        dstB[(size_t)(j0 + row) * HALF + (i0 + tx)] = __float2bfloat16(v);
    }
    __syncthreads();
    #pragma unroll
    for(int l = 0; l < 4; l++){
        int row = ty + l * 8;
        dstT[(size_t)(i0 + row) * HALF + (j0 + tx)] = __float2bfloat16(tile[tx][row]);
    }
}

// K1: Wh[b][h][n][f] = sum_k x[b][n][k] * W[h][k][f]   (fp32)
__global__ void k_wh(const float* __restrict__ x, const float* __restrict__ W,
                     float* __restrict__ Wh){
    __shared__ float xs[32][FF];
    int n0 = blockIdx.x * 32;
    int h  = blockIdx.y;
    int b  = blockIdx.z;
    int t  = threadIdx.x;
    const float* xb = x + ((size_t)b * NN + n0) * FF;
    #pragma unroll
    for(int l = 0; l < 16; l++){
        int idx = l * 256 + t;
        xs[idx >> 7][idx & 127] = xb[idx];
    }
    __syncthreads();
    int f = t & 127, rh = t >> 7;
    float acc[16];
    #pragma unroll
    for(int r = 0; r < 16; r++) acc[r] = 0.f;
    const float* Wp = W + (size_t)h * FF * FF + f;
    for(int k = 0; k < FF; k++){
        float w = Wp[(size_t)k * FF];
        #pragma unroll
        for(int r = 0; r < 16; r++) acc[r] += xs[rh * 16 + r][k] * w;
    }
    float* o = Wh + (((size_t)b * HH + h) * NN + n0 + rh * 16) * FF + f;
    #pragma unroll
    for(int r = 0; r < 16; r++) o[(size_t)r * FF] = acc[r];
}

// K2: s/d row dots + zero denom (replaces hipMemsetAsync)
__global__ void k_sd(const float* __restrict__ Wh, const float* __restrict__ a,
                     float* __restrict__ s, float* __restrict__ d, float* __restrict__ denom){
    int gid = blockIdx.x * blockDim.x + threadIdx.x;
    if(gid < BB * HH * NN) denom[gid] = 0.f;
    int wid = threadIdx.x >> 6, lane = threadIdx.x & 63;
    int row = blockIdx.x * 4 + wid;
    int h = (row / NN) & (HH - 1);
    const float* wr = Wh + (size_t)row * FF;
    float v0 = wr[lane], v1 = wr[lane + 64];
    const float* ah = a + (size_t)h * 2 * FF;
    float ps = v0 * ah[lane]      + v1 * ah[lane + 64];
    float pd = v0 * ah[FF + lane] + v1 * ah[FF + lane + 64];
    #pragma unroll
    for(int m = 32; m >= 1; m >>= 1){
        ps += __shfl_xor(ps, m);
        pd += __shfl_xor(pd, m);
    }
    if(lane == 0){ s[row] = ps; d[row] = pd; }
}

// K3: P (bf16, MFMA-A-fragment layout) + column-sum denom via atomics.
// P offset = ((slice*64 + mtg)*32 + ktg)*512 + lane*8, slice = bb*4+h.
// grid: x = jt(8: 128 j), y = it(32: 32 i), z = bb(4). block 256 (4 blocks/CU).
__global__ __launch_bounds__(256) void k_att(const int* __restrict__ adj,
        const __hip_bfloat16* __restrict__ wvRM, const __hip_bfloat16* __restrict__ wvTp,
        const float* __restrict__ s, const float* __restrict__ d,
        short* __restrict__ P, float* __restrict__ denom){
    int t = threadIdx.x;
    int w = t >> 6, lane = t & 63, q = lane >> 4, r = lane & 15;
    int jt = blockIdx.x, it = blockIdx.y, bb = blockIdx.z;
    int b = bb >> 1, blk = bb & 1;
    int jl = jt * 128 + w * 32 + q * 8;
    int jg = blk ? jl : HALF + jl;
    int sl = b * HH;
    float dv_[HH][8];
    #pragma unroll
    for(int h = 0; h < HH; h++){
        const float* dp = d + (size_t)(sl + h) * NN + jg;
        float4 d0 = *(const float4*)dp;
        float4 d1 = *(const float4*)(dp + 4);
        dv_[h][0]=d0.x; dv_[h][1]=d0.y; dv_[h][2]=d0.z; dv_[h][3]=d0.w;
        dv_[h][4]=d1.x; dv_[h][5]=d1.y; dv_[h][6]=d1.z; dv_[h][7]=d1.w;
    }
    float accd[HH][8] = {};
    int ktg = jt * 4 + w;
    #pragma unroll
    for(int mtl = 0; mtl < 2; mtl++){
        int iloc = it * 32 + mtl * 16 + r;
        int ig = blk ? HALF + iloc : iloc;
        const int* ap = adj + ((size_t)b * NN + ig) * NN + jg;
        int4 A0 = *(const int4*)ap;
        int4 A1 = *(const int4*)(ap + 4);
        int aa[8] = {A0.x, A0.y, A0.z, A0.w, A1.x, A1.y, A1.z, A1.w};
        const short* wp = (const short*)(blk ? wvRM : wvTp) + ((size_t)b * HALF + iloc) * HALF + jl;
        short8 wb = *(const short8*)wp;
        float wm[8];
        #pragma unroll
        for(int e = 0; e < 8; e++) wm[e] = aa[e] > 0 ? bf2f(wb[e]) : 0.f;
        int mtg = it * 2 + mtl;
        #pragma unroll
        for(int h = 0; h < HH; h++){
            float sv = s[(size_t)(sl + h) * NN + ig];
            short8 pk;
            #pragma unroll
            for(int e = 0; e < 8; e++){
                float tt = sv + dv_[h][e];
                tt = tt > 0.f ? tt : 0.2f * tt;
                float pe = __expf(tt) * wm[e];
                accd[h][e] += pe;
                pk[e] = f2bf(pe);
            }
            *(short8*)(P + (((size_t)(bb * HH + h) * 64 + mtg) * 32 + ktg) * 512 + lane * 8) = pk;
        }
    }
    #pragma unroll
    for(int h = 0; h < HH; h++){
        #pragma unroll
        for(int e = 0; e < 8; e++){
            float v = accd[h][e];
            v += __shfl_xor(v, 1);
            v += __shfl_xor(v, 2);
            v += __shfl_xor(v, 4);
            v += __shfl_xor(v, 8);
            accd[h][e] = v;
        }
    }
    if(r == 0){
        #pragma unroll
        for(int h = 0; h < HH; h++)
            #pragma unroll
            for(int e = 0; e < 8; e++)
                atomicAdd(&denom[(size_t)(sl + h) * NN + jg + e], accd[h][e]);
    }
}

// K4: WhB (bf16, MFMA-B-fragment layout) = Wh[j][f] * 1/clip(denom[j])
__global__ __launch_bounds__(256) void k_scale(const float* __restrict__ Wh,
        const float* __restrict__ denom, short* __restrict__ WhB){
    int t = threadIdx.x, w = t >> 6, lane = t & 63, q = lane >> 4, r = lane & 15;
    int kt = blockIdx.x, h = blockIdx.y, b = blockIdx.z;
    int sl = b * HH + h;
    int jb = kt * 32 + q * 8;
    const float* dp = denom + (size_t)sl * NN + jb;
    float4 D0 = *(const float4*)dp;
    float4 D1 = *(const float4*)(dp + 4);
    float dn[8] = {D0.x,D0.y,D0.z,D0.w,D1.x,D1.y,D1.z,D1.w};
    float inv[8];
    #pragma unroll
    for(int e = 0; e < 8; e++) inv[e] = 1.f / fmaxf(dn[e], 1e-12f);
    #pragma unroll
    for(int ntl = 0; ntl < 2; ntl++){
        int nt = w + ntl * 4;
        int f = nt * 16 + r;
        short8 pk;
        #pragma unroll
        for(int e = 0; e < 8; e++){
            float v = Wh[((size_t)sl * NN + jb + e) * FF + f] * inv[e];
            pk[e] = f2bf(v);
        }
        *(short8*)(WhB + (((size_t)sl * 8 + nt) * 64 + kt) * 512 + lane * 8) = pk;
    }
}

// K5: out = ELU(P @ WhB). BM=32, grid (32,4,4)=512 blocks, 4 waves (2m x 2n).
// LDS frags per buf: [0,1]=A(mtg 0,1), [2..9]=B(nt 0..7). 1KB per frag.
__global__ __launch_bounds__(256) void k_pv(const short* __restrict__ P,
        const short* __restrict__ WhB, float* __restrict__ out){
    __shared__ short lds[2][5120];
    int t = threadIdx.x;
    int w = t >> 6, lane = t & 63;
    int wm = w >> 1, wn = w & 1;
    int mt = blockIdx.x, h = blockIdx.y, bb = blockIdx.z;
    int b = bb >> 1, blk = bb & 1;
    size_t Pbase = ((size_t)bb * HH + h) * 64 + mt * 2;
    size_t Bb2 = ((size_t)b * HH + h) * 8;
    int koff = blk ? 0 : 32;   // blk=0 rows attend to global cols 1024..2047
    f32x4 acc[4] = {};
    short8 r0, r1, r2;
    // staging: 640 short8 loads; idx<128 -> P frag (idx>>6), else B frag ((idx-128)>>6)
#define SADDR(IDX, KT) ((IDX) < 128 ? \
    (P + ((Pbase + ((IDX) >> 6)) * 32 + (KT)) * 512 + ((IDX) & 63) * 8) : \
    (WhB + ((Bb2 + (((IDX) - 128) >> 6)) * 64 + koff + (KT)) * 512 + (((IDX) - 128) & 63) * 8))
#define LOADST(KT) { \
    r0 = *(const short8*)SADDR(t, KT); \
    r1 = *(const short8*)SADDR(t + 256, KT); \
    if(t < 128) r2 = *(const short8*)SADDR(t + 512, KT); }
#define WRITEST(BUF) { \
    *(short8*)&lds[BUF][t * 8] = r0; \
    *(short8*)&lds[BUF][(t + 256) * 8] = r1; \
    if(t < 128) *(short8*)&lds[BUF][(t + 512) * 8] = r2; }
    LOADST(0)
    WRITEST(0)
    __syncthreads();
    for(int kt = 0; kt < 32; kt++){
        int cur = kt & 1;
        if(kt < 31){ LOADST(kt + 1) }
        short8 af = *(const short8*)&lds[cur][(wm * 64 + lane) * 8];
        short8 bf[4];
        #pragma unroll
        for(int ni = 0; ni < 4; ni++)
            bf[ni] = *(const short8*)&lds[cur][((2 + wn * 4 + ni) * 64 + lane) * 8];
        #pragma unroll
        for(int ni = 0; ni < 4; ni++)
            acc[ni] = __builtin_amdgcn_mfma_f32_16x16x32_bf16(af, bf[ni], acc[ni], 0, 0, 0);
        __syncthreads();
        if(kt < 31){
            WRITEST(cur ^ 1)
            __syncthreads();
        }
    }
    int rq = lane >> 4, rc = lane & 15;
    int rowg0 = (blk ? HALF : 0) + mt * 32 + wm * 16;
    #pragma unroll
    for(int ni = 0; ni < 4; ni++){
        int f = (wn * 4 + ni) * 16 + rc;
        #pragma unroll
        for(int rg = 0; rg < 4; rg++){
            float v = acc[ni][rg];
            v = v > 0.f ? v : expm1f(v);
            out[((size_t)b * NN + rowg0 + rq * 4 + rg) * (HH * FF) + h * FF + f] = v;
        }
    }
#undef SADDR
#undef LOADST
#undef WRITEST
}

extern "C" void kernel_launch(void* const* d_in, const int* in_sizes, int n_in,
                              void* d_out, int out_size, void* d_ws, size_t ws_size,
                              hipStream_t stream){
    const float* x   = (const float*)d_in[0];
    const float* wv  = (const float*)d_in[1];
    const float* W   = (const float*)d_in[2];
    const float* a   = (const float*)d_in[3];
    const int*   adj = (const int*)d_in[4];
    float* out = (float*)d_out;

    char* ws = (char*)d_ws;
    short*          P     = (short*)ws;                          // 33,554,432 B
    float*          Wh    = (float*)(ws + 33554432);             //  8,388,608 B
    short*          WhB   = (short*)(ws + 41943040);             //  4,194,304 B
    __hip_bfloat16* wvT   = (__hip_bfloat16*)(ws + 46137344);    //  4,194,304 B
    __hip_bfloat16* wvB   = (__hip_bfloat16*)(ws + 50331648);    //  4,194,304 B
    float*          s     = (float*)(ws + 54525952);             //     65,536 B
    float*          dv    = (float*)(ws + 54591488);             //     65,536 B
    float*          denom = (float*)(ws + 54657024);             //     65,536 B

    k_transpose<<<dim3(32, 32, BB), 256, 0, stream>>>(wv, wvT, wvB);
    k_wh<<<dim3(64, HH, BB), 256, 0, stream>>>(x, W, Wh);
    k_sd<<<dim3(4096), 256, 0, stream>>>(Wh, a, s, dv, denom);
    k_att<<<dim3(8, 32, 4), 256, 0, stream>>>(adj, wvB, wvT, s, dv, P, denom);
    k_scale<<<dim3(64, HH, BB), 256, 0, stream>>>(Wh, denom, WhB);
    k_pv<<<dim3(32, HH, 4), 256, 0, stream>>>(P, WhB, out);
}